// Round 4
// baseline (121.585 us; speedup 1.0000x reference)
//
#include <hip/hip_runtime.h>

#define B_N 32
#define LQ  1024
#define LK  1024
#define DH  128

typedef __attribute__((ext_vector_type(4))) float    f32x4;
typedef __attribute__((ext_vector_type(8))) short    s16x8;
typedef __attribute__((ext_vector_type(4))) _Float16 f16x4;
typedef __attribute__((ext_vector_type(8))) _Float16 f16x8;

// fp32 -> bf16 round-to-nearest-even
__device__ inline unsigned short f2bf(float f) {
    union { float f; unsigned u; } c; c.f = f;
    unsigned u = c.u;
    u += 0x7fffu + ((u >> 16) & 1u);
    return (unsigned short)(u >> 16);
}

// logit2 = score * (1/sqrt(128)) * log2(e)
#define ESCALE 0.12751743f

// async global->LDS, 16B per lane (dest must be wave-uniform base + lane*16)
#define G2L16(gp, lp) __builtin_amdgcn_global_load_lds(                         \
    (const __attribute__((address_space(1))) void*)(gp),                        \
    (__attribute__((address_space(3))) void*)(lp), 16, 0, 0)

// ---------------------------------------------------------------------------
// Prepass, XCD-aligned decode (kept from r3: neutral but harmless, and the
// placement assumption matches attn's swizzle). vl-aware skip unchanged.
// blocks 0..1023: K tiles -> Kb bf16 fragments for QK^T (16x16x32).
// blocks 1024..2047: V tiles -> Vt f16 fragment-PAIRS for PV (16x16x16).
// ---------------------------------------------------------------------------
__global__ __launch_bounds__(256)
void prep_kv(const float* __restrict__ K, const float* __restrict__ V,
             const int* __restrict__ VL,
             unsigned short* __restrict__ Kb, _Float16* __restrict__ Vt)
{
    __shared__ float tl[32 * 132];
    const int tid  = threadIdx.x;
    const int lane = tid & 63;
    const int wv   = tid >> 6;
    const int n    = lane & 15;
    const int quad = lane >> 4;

    const int  idx = blockIdx.x;
    const bool isK = (idx >> 10) == 0;
    const int  b   = (idx & 7) | (((idx >> 3) & 3) << 3);
    const int  kt  = (idx >> 5) & 31;

    const int vl = VL[b];
    if (isK) {
        if (vl <= 0 || kt >= 2 * ((vl + 63) >> 6)) return;   // block-uniform
    } else {
        const int nch = (vl > 0) ? ((vl + 63) >> 6) : 16;
        if (kt >= 2 * nch) return;                           // block-uniform
    }

    const float4* src = (const float4*)((isK ? K : V) + ((size_t)b * LK + kt * 32) * DH);
    #pragma unroll
    for (int h = 0; h < 4; ++h) {
        const int i2 = h * 256 + tid;
        const int row = i2 >> 5, c4 = i2 & 31;
        *(float4*)&tl[row * 132 + c4 * 4] = src[i2];
    }
    __syncthreads();

    if (isK) {
        union { s16x8 v; unsigned short u[8]; } t8;
        #pragma unroll
        for (int h = 0; h < 2; ++h) {
            const int f = wv * 2 + h;
            const int tt2 = f >> 2, s = f & 3;
            const float* p = &tl[(tt2 * 16 + n) * 132 + s * 32 + quad * 8];
            const float4 a = *(const float4*)p;
            const float4 c = *(const float4*)(p + 4);
            t8.u[0] = f2bf(a.x); t8.u[1] = f2bf(a.y); t8.u[2] = f2bf(a.z); t8.u[3] = f2bf(a.w);
            t8.u[4] = f2bf(c.x); t8.u[5] = f2bf(c.y); t8.u[6] = f2bf(c.z); t8.u[7] = f2bf(c.w);
            const int w = b * 256 + (kt * 2 + tt2) * 4 + s;
            *(s16x8*)(Kb + (size_t)w * 512 + lane * 8) = t8.v;
        }
    } else {
        #pragma unroll
        for (int h = 0; h < 2; ++h) {
            const int f  = wv * 2 + h;
            const int kg = f >> 2, dp = f & 3;
            f16x8 t8;
            #pragma unroll
            for (int i = 0; i < 4; ++i) {
                const float* row = &tl[(kg * 16 + quad * 4 + i) * 132 + dp * 32 + n];
                t8[i]     = (_Float16)row[0];
                t8[4 + i] = (_Float16)row[16];
            }
            const int v = (b * 64 + kt * 2 + kg) * 4 + dp;
            *(f16x8*)(Vt + (size_t)v * 512 + lane * 8) = t8;
        }
    }
}

// ---------------------------------------------------------------------------
// Attention v4: 2 waves x 32 q-rows (the round-4 change).
// r3 post-mortem: XCD alignment was a null -> the limiter is on-CU. Cost
// model: every wave reads the FULL 32KB K+V chunk from LDS (fragment
// addresses are wave-independent), so LDS traffic = waves-per-chunk x
// chunk bytes. r2/r3: 4 waves -> 17 inst/CU x 128 ds_read_b128 x 12cyc
// ~ 11us of LDS pipe + 2-phase barrier losses ~= the observed ~32us.
// v4 halves amplification: 2 waves/block, each owning TWO 16-row qtiles
// (round-0's proven st0/st1 pattern: one kf read feeds 2 MFMAs, one w8
// feeds 4). Same grid (512), same 64-row block, same 64KB double-buffered
// LDS, same STAGE/vmcnt(0)/s_barrier schedule, same chunk order & mask ->
// numerics identical. Per-CU LDS cycles halve (~5.4us); MFMA total
// unchanged; ~170 VGPR/wave, occupancy 2 blocks x 2 waves / CU.
// Register rule: never index a register array with a runtime value — all
// register indices below are compile-time constants.
// Block swizzle unchanged (bijective, XCD-affine per batch).
// Transposed-S trick unchanged: S^T = K.Q^T C-layout == A-operand layout
// of 16x16x16 f16 MFMA -> exp2(S^T) feeds PV directly.
// ---------------------------------------------------------------------------
__global__ __launch_bounds__(128)
void attn_fwd(const float* __restrict__ Q, const unsigned short* __restrict__ Kb,
              const _Float16* __restrict__ Vt, const int* __restrict__ VL,
              float* __restrict__ O)
{
    __shared__ __align__(16) unsigned short bufK[2][16 * 512];  // 16 KB / buf
    __shared__ __align__(16) _Float16       bufV[2][16 * 512];  // 16 KB / buf

    const int tid  = threadIdx.x;
    const int lane = tid & 63;
    const int w    = tid >> 6;     // wave id (0..1), owns q-rows [w*32, w*32+32)
    const int quad = lane >> 4;
    const int m16  = lane & 15;

    const int idx = blockIdx.x;
    const int qg  = (idx >> 5) & 15;
    const int b   = (idx & 7) | ((((idx >> 3) + (idx >> 8)) & 3) << 3);
    const int q0  = qg * 64;

    const int vl  = VL[b];
    const int nch = (vl > 0) ? ((vl + 63) >> 6) : 16;
    const float emaskval = (vl == 0) ? 1.0f : 0.0f;

    // Q fragments for this wave's TWO qtiles (B-operand of transposed QK^T)
    s16x8 qf[2][4];
    #pragma unroll
    for (int h = 0; h < 2; ++h) {
        const float* qrow = Q + ((size_t)b * LQ + q0 + w * 32 + h * 16 + m16) * DH + quad * 8;
        #pragma unroll
        for (int s = 0; s < 4; ++s) {
            const float4 a = *(const float4*)(qrow + s * 32);
            const float4 c = *(const float4*)(qrow + s * 32 + 4);
            union { s16x8 v; unsigned short u[8]; } t;
            t.u[0] = f2bf(a.x); t.u[1] = f2bf(a.y); t.u[2] = f2bf(a.z); t.u[3] = f2bf(a.w);
            t.u[4] = f2bf(c.x); t.u[5] = f2bf(c.y); t.u[6] = f2bf(c.z); t.u[7] = f2bf(c.w);
            qf[h][s] = t.v;
        }
    }

    f32x4 o[2][8];
    #pragma unroll
    for (int h = 0; h < 2; ++h)
        #pragma unroll
        for (int dt = 0; dt < 8; ++dt) o[h][dt] = (f32x4){0.f, 0.f, 0.f, 0.f};
    float lrun[2] = {0.f, 0.f};

    // chunk t occupies shorts [t*8192, (t+1)*8192) of this batch's Kb / Vt
    const unsigned short* kg0 = Kb + (size_t)b * (256 * 512);
    const _Float16*       vg0 = Vt + (size_t)b * (256 * 512);
    const int co = tid * 8;  // 16B slot; 128 threads x 8 its x 16B = 16KB

    // STAGE(c, t): 16 x global_load_lds dwordx4 per thread (8 K + 8 V)
#define STAGE(c, t)                                                             \
    do {                                                                        \
        const unsigned short* gk_ = kg0 + (size_t)(t) * 8192;                   \
        const _Float16*       gv_ = vg0 + (size_t)(t) * 8192;                   \
        _Pragma("unroll")                                                       \
        for (int it_ = 0; it_ < 8; ++it_)                                       \
            G2L16(gk_ + it_ * 1024 + co, &bufK[c][it_ * 1024 + co]);            \
        _Pragma("unroll")                                                       \
        for (int it_ = 0; it_ < 8; ++it_)                                       \
            G2L16(gv_ + it_ * 1024 + co, &bufV[c][it_ * 1024 + co]);            \
    } while (0)

    // prologue: land chunk 0
    STAGE(0, 0);
    asm volatile("s_waitcnt vmcnt(0)" ::: "memory");
    __builtin_amdgcn_sched_barrier(0);
    __builtin_amdgcn_s_barrier();

    int cur = 0;
    for (int t = 0; t < nch; ++t) {
        if (t + 1 < nch) STAGE(cur ^ 1, t + 1);   // prefetch flies under compute

        const unsigned short* bk = &bufK[cur][0];
        const _Float16*       bv = &bufV[cur][0];
        const bool maskc = (t * 64 + 64 > vl);
        f16x4 pA[2][4];

        // ---- S^T = K Q^T per 16-kpos tile g, softmaxed immediately.
        //      One kf LDS read feeds BOTH qtiles (st0/st1). ----
        #pragma unroll
        for (int g = 0; g < 4; ++g) {
            f32x4 st0 = (f32x4){0.f, 0.f, 0.f, 0.f};
            f32x4 st1 = (f32x4){0.f, 0.f, 0.f, 0.f};
            #pragma unroll
            for (int s = 0; s < 4; ++s) {
                const s16x8 kf = *(const s16x8*)(bk + (g * 4 + s) * 512 + lane * 8);
                st0 = __builtin_amdgcn_mfma_f32_16x16x32_bf16(kf, qf[0][s], st0, 0, 0, 0);
                st1 = __builtin_amdgcn_mfma_f32_16x16x32_bf16(kf, qf[1][s], st1, 0, 0, 0);
            }
            #pragma unroll
            for (int i = 0; i < 4; ++i) {
                float e0 = __builtin_amdgcn_exp2f(st0[i] * ESCALE);
                float e1 = __builtin_amdgcn_exp2f(st1[i] * ESCALE);
                if (maskc && (t * 64 + g * 16 + quad * 4 + i >= vl)) { e0 = emaskval; e1 = emaskval; }
                lrun[0] += e0; lrun[1] += e1;
                pA[0][g][i] = (_Float16)e0;
                pA[1][g][i] = (_Float16)e1;
            }
        }

        // ---- O += P V : one w8 LDS read feeds FOUR MFMAs ----
        #pragma unroll
        for (int g = 0; g < 4; ++g) {
            #pragma unroll
            for (int dp = 0; dp < 4; ++dp) {
                const f16x8 w8 = *(const f16x8*)(bv + (g * 4 + dp) * 512 + lane * 8);
                const f16x4 lo = __builtin_shufflevector(w8, w8, 0, 1, 2, 3);
                const f16x4 hi = __builtin_shufflevector(w8, w8, 4, 5, 6, 7);
                o[0][dp * 2]     = __builtin_amdgcn_mfma_f32_16x16x16f16(pA[0][g], lo, o[0][dp * 2],     0, 0, 0);
                o[0][dp * 2 + 1] = __builtin_amdgcn_mfma_f32_16x16x16f16(pA[0][g], hi, o[0][dp * 2 + 1], 0, 0, 0);
                o[1][dp * 2]     = __builtin_amdgcn_mfma_f32_16x16x16f16(pA[1][g], lo, o[1][dp * 2],     0, 0, 0);
                o[1][dp * 2 + 1] = __builtin_amdgcn_mfma_f32_16x16x16f16(pA[1][g], hi, o[1][dp * 2 + 1], 0, 0, 0);
            }
        }

        // next buffer landed + everyone done reading cur -> safe to swap
        asm volatile("s_waitcnt vmcnt(0)" ::: "memory");
        __builtin_amdgcn_sched_barrier(0);
        __builtin_amdgcn_s_barrier();
        cur ^= 1;
    }
#undef STAGE

    // ---- epilogue: wave owns rows [q0+w*32, q0+w*32+32), two qtiles ----
    #pragma unroll
    for (int h = 0; h < 2; ++h) {
        float L = lrun[h];
        L += __shfl_xor(L, 16);
        L += __shfl_xor(L, 32);
        const size_t obase = ((size_t)b * LQ + q0 + w * 32 + h * 16 + quad * 4) * DH + m16;
        #pragma unroll
        for (int r = 0; r < 4; ++r) {
            const float inv = 1.0f / __shfl(L, quad * 4 + r);
            #pragma unroll
            for (int dt = 0; dt < 8; ++dt)
                O[obase + (size_t)r * DH + dt * 16] = o[h][dt][r] * inv;
        }
    }
}

extern "C" void kernel_launch(void* const* d_in, const int* in_sizes, int n_in,
                              void* d_out, int out_size, void* d_ws, size_t ws_size,
                              hipStream_t stream) {
    const float* Q  = (const float*)d_in[0];
    const float* K  = (const float*)d_in[1];
    const float* V  = (const float*)d_in[2];
    const int*   VL = (const int*)d_in[3];
    float* O = (float*)d_out;
    (void)in_sizes; (void)n_in; (void)out_size; (void)ws_size;

    unsigned short* Kb = (unsigned short*)d_ws;                      // 8 MB K fragments
    _Float16*       Vt = (_Float16*)(Kb + (size_t)B_N * 256 * 512);  // 8 MB V frag-pairs

    prep_kv<<<dim3(2048), dim3(256), 0, stream>>>(K, V, VL, Kb, Vt);
    attn_fwd<<<dim3(B_N * (LQ / 64)), dim3(128), 0, stream>>>(Q, Kb, Vt, VL, O);
}

// Round 5
// 113.849 us; speedup vs baseline: 1.0680x; 1.0680x over previous
//
#include <hip/hip_runtime.h>

#define B_N 32
#define LQ  1024
#define LK  1024
#define DH  128

typedef __attribute__((ext_vector_type(4))) float    f32x4;
typedef __attribute__((ext_vector_type(8))) short    s16x8;
typedef __attribute__((ext_vector_type(4))) _Float16 f16x4;
typedef __attribute__((ext_vector_type(8))) _Float16 f16x8;

// fp32 -> bf16 round-to-nearest-even
__device__ inline unsigned short f2bf(float f) {
    union { float f; unsigned u; } c; c.f = f;
    unsigned u = c.u;
    u += 0x7fffu + ((u >> 16) & 1u);
    return (unsigned short)(u >> 16);
}

// logit2 = score * (1/sqrt(128)) * log2(e)
#define ESCALE 0.12751743f

// async global->LDS, 16B per lane (dest must be wave-uniform base + lane*16)
#define G2L16(gp, lp) __builtin_amdgcn_global_load_lds(                         \
    (const __attribute__((address_space(1))) void*)(gp),                        \
    (__attribute__((address_space(3))) void*)(lp), 16, 0, 0)

// ---------------------------------------------------------------------------
// Prepass, XCD-aligned decode (neutral, kept). vl-aware skip unchanged.
// blocks 0..1023: K tiles -> Kb bf16 fragments for QK^T (16x16x32).
// blocks 1024..2047: V tiles -> Vt f16 fragment-PAIRS for PV (16x16x16).
// ---------------------------------------------------------------------------
__global__ __launch_bounds__(256)
void prep_kv(const float* __restrict__ K, const float* __restrict__ V,
             const int* __restrict__ VL,
             unsigned short* __restrict__ Kb, _Float16* __restrict__ Vt)
{
    __shared__ float tl[32 * 132];
    const int tid  = threadIdx.x;
    const int lane = tid & 63;
    const int wv   = tid >> 6;
    const int n    = lane & 15;
    const int quad = lane >> 4;

    const int  idx = blockIdx.x;
    const bool isK = (idx >> 10) == 0;
    const int  b   = (idx & 7) | (((idx >> 3) & 3) << 3);
    const int  kt  = (idx >> 5) & 31;

    const int vl = VL[b];
    if (isK) {
        if (vl <= 0 || kt >= 2 * ((vl + 63) >> 6)) return;   // block-uniform
    } else {
        const int nch = (vl > 0) ? ((vl + 63) >> 6) : 16;
        if (kt >= 2 * nch) return;                           // block-uniform
    }

    const float4* src = (const float4*)((isK ? K : V) + ((size_t)b * LK + kt * 32) * DH);
    #pragma unroll
    for (int h = 0; h < 4; ++h) {
        const int i2 = h * 256 + tid;
        const int row = i2 >> 5, c4 = i2 & 31;
        *(float4*)&tl[row * 132 + c4 * 4] = src[i2];
    }
    __syncthreads();

    if (isK) {
        union { s16x8 v; unsigned short u[8]; } t8;
        #pragma unroll
        for (int h = 0; h < 2; ++h) {
            const int f = wv * 2 + h;
            const int tt2 = f >> 2, s = f & 3;
            const float* p = &tl[(tt2 * 16 + n) * 132 + s * 32 + quad * 8];
            const float4 a = *(const float4*)p;
            const float4 c = *(const float4*)(p + 4);
            t8.u[0] = f2bf(a.x); t8.u[1] = f2bf(a.y); t8.u[2] = f2bf(a.z); t8.u[3] = f2bf(a.w);
            t8.u[4] = f2bf(c.x); t8.u[5] = f2bf(c.y); t8.u[6] = f2bf(c.z); t8.u[7] = f2bf(c.w);
            const int w = b * 256 + (kt * 2 + tt2) * 4 + s;
            *(s16x8*)(Kb + (size_t)w * 512 + lane * 8) = t8.v;
        }
    } else {
        #pragma unroll
        for (int h = 0; h < 2; ++h) {
            const int f  = wv * 2 + h;
            const int kg = f >> 2, dp = f & 3;
            f16x8 t8;
            #pragma unroll
            for (int i = 0; i < 4; ++i) {
                const float* row = &tl[(kg * 16 + quad * 4 + i) * 132 + dp * 32 + n];
                t8[i]     = (_Float16)row[0];
                t8[4 + i] = (_Float16)row[16];
            }
            const int v = (b * 64 + kt * 2 + kg) * 4 + dp;
            *(f16x8*)(Vt + (size_t)v * 512 + lane * 8) = t8;
        }
    }
}

// ---------------------------------------------------------------------------
// Attention v5: r2's 4-wave x 16-row structure + DEPTH-2 COUNTED-VMCNT
// pipeline (the round-5 change; guide T4).
// r4 post-mortem: LDS traffic was never the binder (1 wave/SIMD exposure
// made r4 WORSE). r2's per-chunk serial path = compute (~1500cy) + FULL
// DMA DRAIN (vmcnt(0) on the 32KB STAGE issued the same iteration) +
// barriers ~= 5-6.5k cyc -> x ~12-16 concurrent chunk-slots/CU = 32us.
// v5 removes the drain: prologue stages chunks 0 AND 1; each iter waits
// vmcnt(8) (only chunk t+1's 8 per-wave loads still flying -> t landed),
// computes t, barriers, then stages t+2 into the buffer t vacated. DMA
// gets a full iteration to land -> off the critical path. Two barriers
// per chunk: (a) after vmcnt-wait = chunk t visible to ALL waves (each
// wave vmcnt-waits its OWN loads; barrier makes it collective), (b) after
// compute = all waves done reading buf[t&1] before STAGE(t+2) overwrites.
// Numerics identical to r2 (same per-wave chunk order & accumulation).
// Prologue STAGE(1,1) is unguarded: chunk 1 is always inside the 16-chunk
// batch allocation; if nch==1 its (possibly poison) bytes are never read.
// LDS 64KB -> 2 blocks/CU, 8 waves/CU. Register rule: never index a
// register array with a runtime value (buf index t&1 is LDS memory, fine).
// Block swizzle unchanged (bijective, XCD-affine per batch).
// Transposed-S trick unchanged: S^T = K.Q^T C-layout == A-operand layout
// of 16x16x16 f16 MFMA -> exp2(S^T) feeds PV directly.
// ---------------------------------------------------------------------------
__global__ __launch_bounds__(256)
void attn_fwd(const float* __restrict__ Q, const unsigned short* __restrict__ Kb,
              const _Float16* __restrict__ Vt, const int* __restrict__ VL,
              float* __restrict__ O)
{
    __shared__ __align__(16) unsigned short bufK[2][16 * 512];  // 16 KB / buf
    __shared__ __align__(16) _Float16       bufV[2][16 * 512];  // 16 KB / buf

    const int tid  = threadIdx.x;
    const int lane = tid & 63;
    const int w    = tid >> 6;     // wave id == qtile id (16 q-rows each)
    const int quad = lane >> 4;
    const int m16  = lane & 15;

    const int idx = blockIdx.x;
    const int qg  = (idx >> 5) & 15;
    const int b   = (idx & 7) | ((((idx >> 3) + (idx >> 8)) & 3) << 3);
    const int q0  = qg * 64;

    const int vl  = VL[b];
    const int nch = (vl > 0) ? ((vl + 63) >> 6) : 16;
    const float emaskval = (vl == 0) ? 1.0f : 0.0f;

    // Q fragments for this wave's qtile (B-operand of transposed QK^T)
    s16x8 qf[4];
    {
        const float* qrow = Q + ((size_t)b * LQ + q0 + w * 16 + m16) * DH + quad * 8;
        #pragma unroll
        for (int s = 0; s < 4; ++s) {
            const float4 a = *(const float4*)(qrow + s * 32);
            const float4 c = *(const float4*)(qrow + s * 32 + 4);
            union { s16x8 v; unsigned short u[8]; } t;
            t.u[0] = f2bf(a.x); t.u[1] = f2bf(a.y); t.u[2] = f2bf(a.z); t.u[3] = f2bf(a.w);
            t.u[4] = f2bf(c.x); t.u[5] = f2bf(c.y); t.u[6] = f2bf(c.z); t.u[7] = f2bf(c.w);
            qf[s] = t.v;
        }
    }

    f32x4 o[8];
    #pragma unroll
    for (int dt = 0; dt < 8; ++dt) o[dt] = (f32x4){0.f, 0.f, 0.f, 0.f};
    float lrun = 0.f;

    // chunk t occupies shorts [t*8192, (t+1)*8192) of this batch's Kb / Vt
    const unsigned short* kg0 = Kb + (size_t)b * (256 * 512);
    const _Float16*       vg0 = Vt + (size_t)b * (256 * 512);
    const int co = tid * 8;  // this thread's 16B slot within a 16KB chunk copy

    // STAGE(c, t): 8 x global_load_lds dwordx4 per thread (4 K + 4 V)
    //              = 8 vmcnt events per wave
#define STAGE(c, t)                                                             \
    do {                                                                        \
        const unsigned short* gk_ = kg0 + (size_t)(t) * 8192;                   \
        const _Float16*       gv_ = vg0 + (size_t)(t) * 8192;                   \
        _Pragma("unroll")                                                       \
        for (int it_ = 0; it_ < 4; ++it_)                                       \
            G2L16(gk_ + it_ * 2048 + co, &bufK[c][it_ * 2048 + co]);            \
        _Pragma("unroll")                                                       \
        for (int it_ = 0; it_ < 4; ++it_)                                       \
            G2L16(gv_ + it_ * 2048 + co, &bufV[c][it_ * 2048 + co]);            \
    } while (0)

    // prologue: stage chunks 0 and 1 (chunk 1 is always within the batch's
    // 16-chunk allocation; unused/poison bytes are never computed if nch==1)
    STAGE(0, 0);
    STAGE(1, 1);

    for (int t = 0; t < nch; ++t) {
        // wait for chunk t to land: only chunk t+1's 8 per-wave loads may
        // remain in flight. Last iteration: drain everything.
        if (t + 1 < nch) { asm volatile("s_waitcnt vmcnt(8)" ::: "memory"); }
        else             { asm volatile("s_waitcnt vmcnt(0)" ::: "memory"); }
        __builtin_amdgcn_sched_barrier(0);
        __builtin_amdgcn_s_barrier();          // (a) chunk t visible to all waves
        __builtin_amdgcn_sched_barrier(0);

        const unsigned short* bk = &bufK[t & 1][0];
        const _Float16*       bv = &bufV[t & 1][0];
        const bool maskc = (t * 64 + 64 > vl);
        f16x4 pA[4];

        // ---- S^T = K Q^T per 16-kpos tile g, softmaxed immediately ----
        #pragma unroll
        for (int g = 0; g < 4; ++g) {
            f32x4 st = (f32x4){0.f, 0.f, 0.f, 0.f};
            #pragma unroll
            for (int s = 0; s < 4; ++s) {
                const s16x8 kf = *(const s16x8*)(bk + (g * 4 + s) * 512 + lane * 8);
                st = __builtin_amdgcn_mfma_f32_16x16x32_bf16(kf, qf[s], st, 0, 0, 0);
            }
            #pragma unroll
            for (int i = 0; i < 4; ++i) {
                float e = __builtin_amdgcn_exp2f(st[i] * ESCALE);
                if (maskc && (t * 64 + g * 16 + quad * 4 + i >= vl)) e = emaskval;
                lrun += e;
                pA[g][i] = (_Float16)e;
            }
        }

        // ---- O += P V : 4 kpos-tiles x 4 d-pairs ----
        #pragma unroll
        for (int g = 0; g < 4; ++g) {
            #pragma unroll
            for (int dp = 0; dp < 4; ++dp) {
                const f16x8 w8 = *(const f16x8*)(bv + (g * 4 + dp) * 512 + lane * 8);
                const f16x4 lo = __builtin_shufflevector(w8, w8, 0, 1, 2, 3);
                const f16x4 hi = __builtin_shufflevector(w8, w8, 4, 5, 6, 7);
                o[dp * 2]     = __builtin_amdgcn_mfma_f32_16x16x16f16(pA[g], lo, o[dp * 2],     0, 0, 0);
                o[dp * 2 + 1] = __builtin_amdgcn_mfma_f32_16x16x16f16(pA[g], hi, o[dp * 2 + 1], 0, 0, 0);
            }
        }

        __builtin_amdgcn_s_barrier();          // (b) all waves done reading buf[t&1]
        __builtin_amdgcn_sched_barrier(0);
        if (t + 2 < nch) STAGE(t & 1, t + 2);  // overwrite the vacated buffer
    }
#undef STAGE

    // ---- epilogue: no split-K merge; wave owns its 16 rows outright ----
    float L = lrun;
    L += __shfl_xor(L, 16);
    L += __shfl_xor(L, 32);
    const size_t obase = ((size_t)b * LQ + q0 + w * 16 + quad * 4) * DH + m16;
    #pragma unroll
    for (int r = 0; r < 4; ++r) {
        const float inv = 1.0f / __shfl(L, quad * 4 + r);
        #pragma unroll
        for (int dt = 0; dt < 8; ++dt)
            O[obase + (size_t)r * DH + dt * 16] = o[dt][r] * inv;
    }
}

extern "C" void kernel_launch(void* const* d_in, const int* in_sizes, int n_in,
                              void* d_out, int out_size, void* d_ws, size_t ws_size,
                              hipStream_t stream) {
    const float* Q  = (const float*)d_in[0];
    const float* K  = (const float*)d_in[1];
    const float* V  = (const float*)d_in[2];
    const int*   VL = (const int*)d_in[3];
    float* O = (float*)d_out;
    (void)in_sizes; (void)n_in; (void)out_size; (void)ws_size;

    unsigned short* Kb = (unsigned short*)d_ws;                      // 8 MB K fragments
    _Float16*       Vt = (_Float16*)(Kb + (size_t)B_N * 256 * 512);  // 8 MB V frag-pairs

    prep_kv<<<dim3(2048), dim3(256), 0, stream>>>(K, V, VL, Kb, Vt);
    attn_fwd<<<dim3(B_N * (LQ / 64)), dim3(256), 0, stream>>>(Q, Kb, Vt, VL, O);
}